// Round 3
// baseline (544.483 us; speedup 1.0000x reference)
//
#include <hip/hip_runtime.h>
#include <cstdint>

#define H 128
#define NNODES 20000
#define NEDGES 640000
#define TILE 64
#define SCAN_BLOCKS 20

typedef unsigned short ushort_t;
typedef __attribute__((ext_vector_type(8))) short short8;
typedef __attribute__((ext_vector_type(4))) float floatx4;

__device__ __forceinline__ ushort_t f2bf(float f){
  uint32_t u = __builtin_bit_cast(uint32_t, f);
  u += 0x7fffu + ((u >> 16) & 1u);           // RNE
  return (ushort_t)(u >> 16);
}
__device__ __forceinline__ float bf2f(ushort_t s){
  uint32_t u = ((uint32_t)s) << 16;
  return __builtin_bit_cast(float, u);
}
// fast silu: v_exp_f32 + v_rcp_f32
__device__ __forceinline__ float silu_f(float x){
  float e = __builtin_amdgcn_exp2f(-1.44269504089f * x);
  return x * __builtin_amdgcn_rcpf(1.f + e);
}

// ---------------- setup: weight transpose+cvt, h cvt, degree histogram ------
__global__ void setup_kernel(const float* __restrict__ eW1, const float* __restrict__ eW2,
                             const float* __restrict__ cW1, const float* __restrict__ nW1,
                             const float* __restrict__ nW2, const float* __restrict__ h,
                             const int* __restrict__ ei,
                             ushort_t* __restrict__ eW1t, ushort_t* __restrict__ eW2t,
                             ushort_t* __restrict__ cW1t, ushort_t* __restrict__ nW1t,
                             ushort_t* __restrict__ nW2t, ushort_t* __restrict__ hb,
                             int* __restrict__ hist){
  int idx = blockIdx.x * 256 + threadIdx.x;
  if (idx < 32768){                      // eW1t[n*256+k] = eW1[k*128+n], k<256
    int n = idx >> 8, k = idx & 255;
    eW1t[idx] = f2bf(eW1[k * H + n]);
  } else if (idx < 49152){
    int j = idx - 32768; int n = j >> 7, k = j & 127;
    eW2t[j] = f2bf(eW2[k * H + n]);
  } else if (idx < 65536){
    int j = idx - 49152; int n = j >> 7, k = j & 127;
    cW1t[j] = f2bf(cW1[k * H + n]);
  } else if (idx < 98304){
    int j = idx - 65536; int n = j >> 8, k = j & 255;
    nW1t[j] = f2bf(nW1[k * H + n]);
  } else if (idx < 114688){
    int j = idx - 98304; int n = j >> 7, k = j & 127;
    nW2t[j] = f2bf(nW2[k * H + n]);
  } else if (idx < 434688){              // h fp32 -> bf16, 8 elems/thread
    int k = idx - 114688;
    const float4* p = (const float4*)(h + (size_t)k * 8);
    float4 v0 = p[0], v1 = p[1];
    ushort_t tmp[8];
    tmp[0]=f2bf(v0.x); tmp[1]=f2bf(v0.y); tmp[2]=f2bf(v0.z); tmp[3]=f2bf(v0.w);
    tmp[4]=f2bf(v1.x); tmp[5]=f2bf(v1.y); tmp[6]=f2bf(v1.z); tmp[7]=f2bf(v1.w);
    *(short8*)(hb + (size_t)k * 8) = *(const short8*)tmp;
  } else {                               // degree histogram
    int j = idx - 434688;
    if (j < NEDGES) atomicAdd(&hist[ei[j]], 1);
  }
}

// ---------------- CSR build ------------------------------------------------
__global__ void scanA_kernel(const int* __restrict__ hist, int* __restrict__ head,
                             int* __restrict__ totals){
  __shared__ int s[1024];
  const int t = threadIdx.x;
  const int idx = blockIdx.x * 1024 + t;
  int v = (idx < NNODES) ? hist[idx] : 0;
  s[t] = v;
  __syncthreads();
  for (int off = 1; off < 1024; off <<= 1){
    int tmp = (t >= off) ? s[t - off] : 0;
    __syncthreads();
    s[t] += tmp;
    __syncthreads();
  }
  if (idx < NNODES) head[idx] = s[t] - v;          // exclusive within block
  if (t == 1023) totals[blockIdx.x] = s[t];
}

__global__ void scanB_kernel(const int* __restrict__ totals, int* __restrict__ offs){
  if (threadIdx.x == 0){
    int acc = 0;
    for (int i = 0; i < SCAN_BLOCKS; i++){ offs[i] = acc; acc += totals[i]; }
  }
}

__global__ void scanC_kernel(const int* __restrict__ offs, int* __restrict__ head){
  int idx = blockIdx.x * 1024 + threadIdx.x;
  if (idx < NNODES) head[idx] += offs[blockIdx.x];
}

__global__ void scatter_kernel(const int* __restrict__ ei, int* __restrict__ head,
                               int2* __restrict__ spair){
  int idx = blockIdx.x * 256 + threadIdx.x;
  if (idx < NEDGES){
    int r = ei[idx], c = ei[NEDGES + idx];
    int p = atomicAdd(&head[r], 1);
    spair[p] = make_int2(r, c);
  }
}

// ---------------- edge kernel ----------------------------------------------
// 64 edges/block (sorted by row), 4 waves; wave owns 32 of 128 output cols.
// B2/B3 fragments prefetched to registers; A for GEMM1 direct from global bf16.
__global__ __launch_bounds__(256, 3) void edge_kernel(
    const ushort_t* __restrict__ hb, const float* __restrict__ pos,
    const int2* __restrict__ spair,
    const float* __restrict__ eW1, const float* __restrict__ eb1,
    const float* __restrict__ eb2, const float* __restrict__ cb1,
    const float* __restrict__ cW2,
    const ushort_t* __restrict__ eW1t, const ushort_t* __restrict__ eW2t,
    const ushort_t* __restrict__ cW1t,
    float* __restrict__ m_i, float* __restrict__ pos_sum)
{
  __shared__ __align__(16) ushort_t bufT[TILE * 136];  // t1 (silu of GEMM1)
  __shared__ __align__(16) ushort_t bufM[TILE * 136];  // m_ij bf16
  __shared__ int   row_l[TILE];
  __shared__ float sq_l[TILE];
  __shared__ float dx_l[TILE], dy_l[TILE], dz_l[TILE], w_l[TILE];

  const int t = threadIdx.x;
  const int base = blockIdx.x * TILE;
  const int lane = t & 63, q = lane >> 4, ln = lane & 15;
  const int nb = (t >> 6) * 32;

  // ---- prefetch B2 (eW2t) and B3 (cW1t) fragments into registers
  short8 b2f[4][2], b3f[4][2];
  #pragma unroll
  for (int ks = 0; ks < 4; ks++)
    #pragma unroll
    for (int nt = 0; nt < 2; nt++){
      b2f[ks][nt] = *(const short8*)(eW2t + (size_t)(nb + nt*16 + ln) * 128 + ks*32 + q*8);
      b3f[ks][nt] = *(const short8*)(cW1t + (size_t)(nb + nt*16 + ln) * 128 + ks*32 + q*8);
    }

  // ---- per-lane A-source rows for the 4 m-tiles (no LDS dependency)
  int2 e[4];
  #pragma unroll
  for (int mt = 0; mt < 4; mt++) e[mt] = spair[base + mt*16 + ln];

  // ---- per-edge geometry into LDS (consumed after barrier A)
  if (t < TILE){
    int2 rc = spair[base + t];
    row_l[t] = rc.x;
    float ax = pos[rc.x*3+0] - pos[rc.y*3+0];
    float ay = pos[rc.x*3+1] - pos[rc.y*3+1];
    float az = pos[rc.x*3+2] - pos[rc.y*3+2];
    dx_l[t] = ax; dy_l[t] = ay; dz_l[t] = az;
    sq_l[t] = ax*ax + ay*ay + az*az;
    w_l[t]  = 0.f;
  }

  const ushort_t* bB0 = eW1t + (size_t)(nb + ln) * 256 + q * 8;
  const ushort_t* bB1 = eW1t + (size_t)(nb + 16 + ln) * 256 + q * 8;

  floatx4 acc[4][2];
  #pragma unroll
  for (int mt = 0; mt < 4; mt++)
    #pragma unroll
    for (int nt = 0; nt < 2; nt++) acc[mt][nt] = (floatx4)0.f;

  // ---- GEMM1: [64 x 256] @ eW1t, A direct from global bf16
  #pragma unroll
  for (int ks = 0; ks < 8; ks++){
    const int sl = (ks & 3) * 32 + q * 8;
    short8 a[4], b[2];
    #pragma unroll
    for (int mt = 0; mt < 4; mt++){
      int src = (ks < 4) ? e[mt].x : e[mt].y;
      a[mt] = *(const short8*)(hb + (size_t)src * H + sl);
    }
    b[0] = *(const short8*)(bB0 + ks * 32);
    b[1] = *(const short8*)(bB1 + ks * 32);
    #pragma unroll
    for (int mt = 0; mt < 4; mt++)
      #pragma unroll
      for (int nt = 0; nt < 2; nt++)
        acc[mt][nt] = __builtin_amdgcn_mfma_f32_16x16x32_bf16(a[mt], b[nt], acc[mt][nt], 0, 0, 0);
  }
  __syncthreads();                                  // barrier A (edge arrays ready)
  {
    float w256v[2], eb1v[2];
    #pragma unroll
    for (int nt = 0; nt < 2; nt++){
      int n = nb + nt*16 + ln;
      w256v[nt] = eW1[256 * H + n];
      eb1v[nt]  = eb1[n];
    }
    #pragma unroll
    for (int mt = 0; mt < 4; mt++)
      #pragma unroll
      for (int r = 0; r < 4; r++){
        int m = mt*16 + q*4 + r;
        float sq = sq_l[m];
        #pragma unroll
        for (int nt = 0; nt < 2; nt++){
          float x = acc[mt][nt][r] + sq * w256v[nt] + eb1v[nt];
          bufT[m * 136 + nb + nt*16 + ln] = f2bf(silu_f(x));
        }
      }
  }
  __syncthreads();                                  // barrier B (bufT ready)

  // ---- GEMM2: t1 @ eW2t -> m_ij   (B from registers)
  #pragma unroll
  for (int mt = 0; mt < 4; mt++)
    #pragma unroll
    for (int nt = 0; nt < 2; nt++) acc[mt][nt] = (floatx4)0.f;
  #pragma unroll
  for (int ks = 0; ks < 4; ks++){
    short8 a[4];
    #pragma unroll
    for (int mt = 0; mt < 4; mt++)
      a[mt] = *(const short8*)(bufT + (mt*16 + ln) * 136 + ks*32 + q*8);
    #pragma unroll
    for (int mt = 0; mt < 4; mt++)
      #pragma unroll
      for (int nt = 0; nt < 2; nt++)
        acc[mt][nt] = __builtin_amdgcn_mfma_f32_16x16x32_bf16(a[mt], b2f[ks][nt], acc[mt][nt], 0, 0, 0);
  }
  {
    float eb2v[2];
    #pragma unroll
    for (int nt = 0; nt < 2; nt++) eb2v[nt] = eb2[nb + nt*16 + ln];
    #pragma unroll
    for (int mt = 0; mt < 4; mt++)
      #pragma unroll
      for (int r = 0; r < 4; r++){
        int m = mt*16 + q*4 + r;
        #pragma unroll
        for (int nt = 0; nt < 2; nt++){
          float mv = silu_f(acc[mt][nt][r] + eb2v[nt]);
          bufM[m * 136 + nb + nt*16 + ln] = f2bf(mv);
        }
      }
  }
  __syncthreads();                                  // barrier C (bufM ready)

  // ---- GEMM3: m_ij @ cW1t ; dot with cW2 -> per-edge scalar weight
  #pragma unroll
  for (int mt = 0; mt < 4; mt++)
    #pragma unroll
    for (int nt = 0; nt < 2; nt++) acc[mt][nt] = (floatx4)0.f;
  #pragma unroll
  for (int ks = 0; ks < 4; ks++){
    short8 a[4];
    #pragma unroll
    for (int mt = 0; mt < 4; mt++)
      a[mt] = *(const short8*)(bufM + (mt*16 + ln) * 136 + ks*32 + q*8);
    #pragma unroll
    for (int mt = 0; mt < 4; mt++)
      #pragma unroll
      for (int nt = 0; nt < 2; nt++)
        acc[mt][nt] = __builtin_amdgcn_mfma_f32_16x16x32_bf16(a[mt], b3f[ks][nt], acc[mt][nt], 0, 0, 0);
  }
  {
    float cb1v[2], cw2v[2];
    #pragma unroll
    for (int nt = 0; nt < 2; nt++){
      int n = nb + nt*16 + ln;
      cb1v[nt] = cb1[n];
      cw2v[nt] = cW2[n];
    }
    #pragma unroll
    for (int mt = 0; mt < 4; mt++)
      #pragma unroll
      for (int r = 0; r < 4; r++){
        float p = 0.f;
        #pragma unroll
        for (int nt = 0; nt < 2; nt++)
          p += silu_f(acc[mt][nt][r] + cb1v[nt]) * cw2v[nt];
        p += __shfl_xor(p, 1);
        p += __shfl_xor(p, 2);
        p += __shfl_xor(p, 4);
        p += __shfl_xor(p, 8);
        if (ln == 0) atomicAdd(&w_l[mt*16 + q*4 + r], p);
      }
  }
  __syncthreads();                                  // barrier D (w_l, bufM ready)

  // ---- segmented reduce m_ij (rows sorted) -> m_i; 256 threads, 1 col each
  {
    int col = t & 127;
    int ms  = (t >> 7) * 32;
    float a0 = 0.f;
    int cur = row_l[ms];
    #pragma unroll 4
    for (int mm = 0; mm < 32; mm++){
      int m = ms + mm;
      int rr = row_l[m];
      float v = bf2f(bufM[m * 136 + col]);
      if (rr != cur){
        unsafeAtomicAdd(&m_i[(size_t)cur * H + col], a0);
        a0 = 0.f; cur = rr;
      }
      a0 += v;
    }
    unsafeAtomicAdd(&m_i[(size_t)cur * H + col], a0);
  }
  // ---- pos segmented reduce with inline scaling (3 threads)
  if (t < 3){
    const float* src = (t == 0) ? dx_l : (t == 1) ? dy_l : dz_l;
    float accv = 0.f;
    int cur = row_l[0];
    for (int m = 0; m < TILE; m++){
      int rr = row_l[m];
      if (rr != cur){
        unsafeAtomicAdd(&pos_sum[cur*3 + t], accv);
        accv = 0.f; cur = rr;
      }
      float s = __builtin_amdgcn_rsqf(sq_l[m] + 1e-8f) * w_l[m];
      accv += src[m] * s;
    }
    unsafeAtomicAdd(&pos_sum[cur*3 + t], accv);
  }
}

// ---------------- node kernel ----------------------------------------------
__global__ __launch_bounds__(256, 3) void node_kernel(
    const float* __restrict__ h, const ushort_t* __restrict__ hb,
    const float* __restrict__ pos,
    const float* __restrict__ nb1, const float* __restrict__ nb2,
    const ushort_t* __restrict__ nW1t, const ushort_t* __restrict__ nW2t,
    const float* __restrict__ m_i, const float* __restrict__ pos_sum,
    const int* __restrict__ hist,
    float* __restrict__ h_out, float* __restrict__ pos_out)
{
  __shared__ __align__(16) ushort_t bufA[TILE * 264];
  __shared__ __align__(16) ushort_t bufT[TILE * 136];
  const int t = threadIdx.x;
  const int base = blockIdx.x * TILE;

  if (t < TILE){
    int node = base + t;
    if (node < NNODES){
      float c = fmaxf((float)hist[node], 1.f);
      float invc = __builtin_amdgcn_rcpf(c);
      pos_out[node*3+0] = pos[node*3+0] + pos_sum[node*3+0] * invc;
      pos_out[node*3+1] = pos[node*3+1] + pos_sum[node*3+1] * invc;
      pos_out[node*3+2] = pos[node*3+2] + pos_sum[node*3+2] * invc;
    }
  }
  { // gather [h(bf16 copy) | m_i(convert)] -> bufA
    const int i = t >> 2, p = t & 3;
    const int node = base + i;
    ushort_t* dst = bufA + i * 264 + p * 64;
    if (node < NNODES){
      if (p < 2){
        const short8* sp = (const short8*)(hb + (size_t)node * H + p * 64);
        #pragma unroll
        for (int j = 0; j < 8; j++) ((short8*)dst)[j] = sp[j];
      } else {
        const float4* sp = (const float4*)(m_i + (size_t)node * H + (p - 2) * 64);
        #pragma unroll
        for (int j = 0; j < 16; j++){
          float4 v = sp[j];
          dst[j*4+0] = f2bf(v.x); dst[j*4+1] = f2bf(v.y);
          dst[j*4+2] = f2bf(v.z); dst[j*4+3] = f2bf(v.w);
        }
      }
    } else {
      #pragma unroll
      for (int j = 0; j < 8; j++) ((short8*)dst)[j] = (short8)0;
    }
  }
  __syncthreads();

  const int lane = t & 63, q = lane >> 4, ln = lane & 15;
  const int nb_ = (t >> 6) * 32;

  floatx4 acc[4][2];
  #pragma unroll
  for (int mt = 0; mt < 4; mt++)
    #pragma unroll
    for (int nt = 0; nt < 2; nt++) acc[mt][nt] = (floatx4)0.f;
  #pragma unroll
  for (int ks = 0; ks < 8; ks++){
    short8 a[4], b[2];
    #pragma unroll
    for (int mt = 0; mt < 4; mt++)
      a[mt] = *(const short8*)(bufA + (mt*16 + ln) * 264 + ks*32 + q*8);
    #pragma unroll
    for (int nt = 0; nt < 2; nt++)
      b[nt] = *(const short8*)(nW1t + (size_t)(nb_ + nt*16 + ln) * 256 + ks*32 + q*8);
    #pragma unroll
    for (int mt = 0; mt < 4; mt++)
      #pragma unroll
      for (int nt = 0; nt < 2; nt++)
        acc[mt][nt] = __builtin_amdgcn_mfma_f32_16x16x32_bf16(a[mt], b[nt], acc[mt][nt], 0, 0, 0);
  }
  {
    float nb1v[2];
    #pragma unroll
    for (int nt = 0; nt < 2; nt++) nb1v[nt] = nb1[nb_ + nt*16 + ln];
    #pragma unroll
    for (int mt = 0; mt < 4; mt++)
      #pragma unroll
      for (int r = 0; r < 4; r++){
        int m = mt*16 + q*4 + r;
        #pragma unroll
        for (int nt = 0; nt < 2; nt++)
          bufT[m * 136 + nb_ + nt*16 + ln] = f2bf(silu_f(acc[mt][nt][r] + nb1v[nt]));
      }
  }
  __syncthreads();

  #pragma unroll
  for (int mt = 0; mt < 4; mt++)
    #pragma unroll
    for (int nt = 0; nt < 2; nt++) acc[mt][nt] = (floatx4)0.f;
  #pragma unroll
  for (int ks = 0; ks < 4; ks++){
    short8 a[4], b[2];
    #pragma unroll
    for (int mt = 0; mt < 4; mt++)
      a[mt] = *(const short8*)(bufT + (mt*16 + ln) * 136 + ks*32 + q*8);
    #pragma unroll
    for (int nt = 0; nt < 2; nt++)
      b[nt] = *(const short8*)(nW2t + (size_t)(nb_ + nt*16 + ln) * 128 + ks*32 + q*8);
    #pragma unroll
    for (int mt = 0; mt < 4; mt++)
      #pragma unroll
      for (int nt = 0; nt < 2; nt++)
        acc[mt][nt] = __builtin_amdgcn_mfma_f32_16x16x32_bf16(a[mt], b[nt], acc[mt][nt], 0, 0, 0);
  }
  {
    float nb2v[2];
    #pragma unroll
    for (int nt = 0; nt < 2; nt++) nb2v[nt] = nb2[nb_ + nt*16 + ln];
    #pragma unroll
    for (int mt = 0; mt < 4; mt++)
      #pragma unroll
      for (int r = 0; r < 4; r++){
        int m = mt*16 + q*4 + r;
        int node = base + m;
        if (node < NNODES){
          #pragma unroll
          for (int nt = 0; nt < 2; nt++){
            int n = nb_ + nt*16 + ln;
            h_out[(size_t)node * H + n] = h[(size_t)node * H + n] + acc[mt][nt][r] + nb2v[nt];
          }
        }
      }
  }
}

// ---------------- launch ----------------------------------------------------
extern "C" void kernel_launch(void* const* d_in, const int* in_sizes, int n_in,
                              void* d_out, int out_size, void* d_ws, size_t ws_size,
                              hipStream_t stream){
  const float* h   = (const float*)d_in[0];
  const float* pos = (const float*)d_in[1];
  const int*   ei  = (const int*)d_in[2];
  const float* eW1 = (const float*)d_in[3];
  const float* eb1 = (const float*)d_in[4];
  const float* eW2 = (const float*)d_in[5];
  const float* eb2 = (const float*)d_in[6];
  const float* cW1 = (const float*)d_in[7];
  const float* cb1 = (const float*)d_in[8];
  const float* cW2 = (const float*)d_in[9];
  const float* nW1 = (const float*)d_in[10];
  const float* nb1 = (const float*)d_in[11];
  const float* nW2 = (const float*)d_in[12];
  const float* nb2 = (const float*)d_in[13];

  char* ws = (char*)d_ws;
  float*    m_i     = (float*)   (ws);                 // 10,240,000 B
  float*    pos_sum = (float*)   (ws + 10240000);      //    240,000 B
  int*      hist    = (int*)     (ws + 10480000);      //     80,000 B
  int*      head    = (int*)     (ws + 10560000);      //     80,000 B
  int*      totals  = (int*)     (ws + 10640000);      //      2,048 B
  int*      offs    = (int*)     (ws + 10642048);      //      2,048 B
  int2*     spair   = (int2*)    (ws + 10644096);      //  5,120,000 B
  ushort_t* h_bf    = (ushort_t*)(ws + 15764096);      //  5,120,000 B
  ushort_t* eW1t    = (ushort_t*)(ws + 20884096);      //     65,536 B
  ushort_t* eW2t    = (ushort_t*)(ws + 20949632);      //     32,768 B
  ushort_t* cW1t    = (ushort_t*)(ws + 20982400);      //     32,768 B
  ushort_t* nW1t    = (ushort_t*)(ws + 21015168);      //     65,536 B
  ushort_t* nW2t    = (ushort_t*)(ws + 21080704);      //     32,768 B

  hipMemsetAsync(ws, 0, 10560000, stream);             // m_i + pos_sum + hist

  setup_kernel<<<4198, 256, 0, stream>>>(eW1, eW2, cW1, nW1, nW2, h, ei,
                                         eW1t, eW2t, cW1t, nW1t, nW2t, h_bf, hist);
  scanA_kernel<<<SCAN_BLOCKS, 1024, 0, stream>>>(hist, head, totals);
  scanB_kernel<<<1, 64, 0, stream>>>(totals, offs);
  scanC_kernel<<<SCAN_BLOCKS, 1024, 0, stream>>>(offs, head);
  scatter_kernel<<<(NEDGES + 255) / 256, 256, 0, stream>>>(ei, head, spair);

  edge_kernel<<<NEDGES / TILE, 256, 0, stream>>>(h_bf, pos, spair,
                                                 eW1, eb1, eb2, cb1, cW2,
                                                 eW1t, eW2t, cW1t, m_i, pos_sum);

  float* h_out   = (float*)d_out;
  float* pos_out = h_out + (size_t)NNODES * H;
  node_kernel<<<(NNODES + TILE - 1) / TILE, 256, 0, stream>>>(h, h_bf, pos, nb1, nb2,
                                                              nW1t, nW2t, m_i, pos_sum,
                                                              hist, h_out, pos_out);
}

// Round 4
// 449.554 us; speedup vs baseline: 1.2112x; 1.2112x over previous
//
#include <hip/hip_runtime.h>
#include <cstdint>

#define H 128
#define NNODES 20000
#define NEDGES 640000
#define TILE 64
#define SCAN_BLOCKS 20

typedef unsigned short ushort_t;
typedef __attribute__((ext_vector_type(8))) short short8;
typedef __attribute__((ext_vector_type(4))) float floatx4;

__device__ __forceinline__ ushort_t f2bf(float f){
  uint32_t u = __builtin_bit_cast(uint32_t, f);
  u += 0x7fffu + ((u >> 16) & 1u);           // RNE
  return (ushort_t)(u >> 16);
}
__device__ __forceinline__ float bf2f(ushort_t s){
  uint32_t u = ((uint32_t)s) << 16;
  return __builtin_bit_cast(float, u);
}
// fast silu: v_exp_f32 + v_rcp_f32
__device__ __forceinline__ float silu_f(float x){
  float e = __builtin_amdgcn_exp2f(-1.44269504089f * x);
  return x * __builtin_amdgcn_rcpf(1.f + e);
}

// ---- setup: weight transpose+cvt, h cvt, degree histogram, zero m_i/pos_sum
__global__ void setup_kernel(const float* __restrict__ eW1, const float* __restrict__ eW2,
                             const float* __restrict__ cW1, const float* __restrict__ nW1,
                             const float* __restrict__ nW2, const float* __restrict__ h,
                             const int* __restrict__ ei,
                             ushort_t* __restrict__ eW1t, ushort_t* __restrict__ eW2t,
                             ushort_t* __restrict__ cW1t, ushort_t* __restrict__ nW1t,
                             ushort_t* __restrict__ nW2t, ushort_t* __restrict__ hb,
                             int* __restrict__ hist, float4* __restrict__ zbase){
  int idx = blockIdx.x * 256 + threadIdx.x;
  if (idx < 32768){                      // eW1t[n*256+k] = eW1[k*128+n], k<256
    int n = idx >> 8, k = idx & 255;
    eW1t[idx] = f2bf(eW1[k * H + n]);
  } else if (idx < 49152){
    int j = idx - 32768; int n = j >> 7, k = j & 127;
    eW2t[j] = f2bf(eW2[k * H + n]);
  } else if (idx < 65536){
    int j = idx - 49152; int n = j >> 7, k = j & 127;
    cW1t[j] = f2bf(cW1[k * H + n]);
  } else if (idx < 98304){
    int j = idx - 65536; int n = j >> 8, k = j & 255;
    nW1t[j] = f2bf(nW1[k * H + n]);
  } else if (idx < 114688){
    int j = idx - 98304; int n = j >> 7, k = j & 127;
    nW2t[j] = f2bf(nW2[k * H + n]);
  } else if (idx < 434688){              // h fp32 -> bf16, 8 elems/thread
    int k = idx - 114688;
    const float4* p = (const float4*)(h + (size_t)k * 8);
    float4 v0 = p[0], v1 = p[1];
    ushort_t tmp[8];
    tmp[0]=f2bf(v0.x); tmp[1]=f2bf(v0.y); tmp[2]=f2bf(v0.z); tmp[3]=f2bf(v0.w);
    tmp[4]=f2bf(v1.x); tmp[5]=f2bf(v1.y); tmp[6]=f2bf(v1.z); tmp[7]=f2bf(v1.w);
    *(short8*)(hb + (size_t)k * 8) = *(const short8*)tmp;
  } else if (idx < 1074688){             // degree histogram
    int j = idx - 434688;
    atomicAdd(&hist[ei[j]], 1);
  } else {                               // zero m_i + pos_sum (655000 float4s)
    int j = idx - 1074688;
    if (j < 655000) zbase[j] = make_float4(0.f, 0.f, 0.f, 0.f);
  }
}

// ---------------- CSR build ------------------------------------------------
__global__ void scanA_kernel(const int* __restrict__ hist, int* __restrict__ head,
                             int* __restrict__ totals){
  __shared__ int s[1024];
  const int t = threadIdx.x;
  const int idx = blockIdx.x * 1024 + t;
  int v = (idx < NNODES) ? hist[idx] : 0;
  s[t] = v;
  __syncthreads();
  for (int off = 1; off < 1024; off <<= 1){
    int tmp = (t >= off) ? s[t - off] : 0;
    __syncthreads();
    s[t] += tmp;
    __syncthreads();
  }
  if (idx < NNODES) head[idx] = s[t] - v;          // exclusive within block
  if (t == 1023) totals[blockIdx.x] = s[t];
}

__global__ void scanC_kernel(const int* __restrict__ totals, int* __restrict__ head){
  __shared__ int off_s;
  if (threadIdx.x == 0){
    int a = 0;
    for (int i = 0; i < (int)blockIdx.x; i++) a += totals[i];
    off_s = a;
  }
  __syncthreads();
  int idx = blockIdx.x * 1024 + threadIdx.x;
  if (idx < NNODES) head[idx] += off_s;
}

__global__ void scatter_kernel(const int* __restrict__ ei, int* __restrict__ head,
                               int2* __restrict__ spair){
  int idx = blockIdx.x * 256 + threadIdx.x;
  if (idx < NEDGES){
    int r = ei[idx], c = ei[NEDGES + idx];
    int p = atomicAdd(&head[r], 1);
    spair[p] = make_int2(r, c);
  }
}

// ---------------- edge kernel ----------------------------------------------
// 64 edges/block (sorted by row), 4 waves; wave owns 32 of 128 output cols.
// Single reused LDS tile buffer (t1 then m_ij) -> ~19 KB LDS -> 8 blocks/CU.
__global__ __launch_bounds__(256, 4) void edge_kernel(
    const ushort_t* __restrict__ hb, const float* __restrict__ pos,
    const int2* __restrict__ spair,
    const float* __restrict__ eW1, const float* __restrict__ eb1,
    const float* __restrict__ eb2, const float* __restrict__ cb1,
    const float* __restrict__ cW2,
    const ushort_t* __restrict__ eW1t, const ushort_t* __restrict__ eW2t,
    const ushort_t* __restrict__ cW1t,
    float* __restrict__ m_i, float* __restrict__ pos_sum)
{
  __shared__ __align__(16) ushort_t buf[TILE * 136];   // t1, then m_ij
  __shared__ int   row_l[TILE];
  __shared__ int   col_l[TILE];
  __shared__ float sq_l[TILE];
  __shared__ float dx_l[TILE], dy_l[TILE], dz_l[TILE], w_l[TILE];

  const int t = threadIdx.x;
  const int base = blockIdx.x * TILE;

  if (t < TILE){
    int2 rc = spair[base + t];
    row_l[t] = rc.x; col_l[t] = rc.y;
    float ax = pos[rc.x*3+0] - pos[rc.y*3+0];
    float ay = pos[rc.x*3+1] - pos[rc.y*3+1];
    float az = pos[rc.x*3+2] - pos[rc.y*3+2];
    dx_l[t] = ax; dy_l[t] = ay; dz_l[t] = az;
    sq_l[t] = ax*ax + ay*ay + az*az;
    w_l[t]  = 0.f;
  }
  __syncthreads();                                  // sync1: edge arrays ready

  const int lane = t & 63, q = lane >> 4, ln = lane & 15;
  const int nb = (t >> 6) * 32;

  // per-lane A-source rows for the 4 m-tiles
  int rs[4], cs[4];
  #pragma unroll
  for (int mt = 0; mt < 4; mt++){ rs[mt] = row_l[mt*16 + ln]; cs[mt] = col_l[mt*16 + ln]; }

  const ushort_t* bB0 = eW1t + (size_t)(nb + ln) * 256 + q * 8;
  const ushort_t* bB1 = eW1t + (size_t)(nb + 16 + ln) * 256 + q * 8;

  floatx4 acc[4][2];
  #pragma unroll
  for (int mt = 0; mt < 4; mt++)
    #pragma unroll
    for (int nt = 0; nt < 2; nt++) acc[mt][nt] = (floatx4)0.f;

  // ---- GEMM1: [64 x 256] @ eW1t, A direct from global bf16
  #pragma unroll
  for (int ks = 0; ks < 8; ks++){
    const int sl = (ks & 3) * 32 + q * 8;
    short8 a[4], b[2];
    #pragma unroll
    for (int mt = 0; mt < 4; mt++){
      int src = (ks < 4) ? rs[mt] : cs[mt];
      a[mt] = *(const short8*)(hb + (size_t)src * H + sl);
    }
    b[0] = *(const short8*)(bB0 + ks * 32);
    b[1] = *(const short8*)(bB1 + ks * 32);
    #pragma unroll
    for (int mt = 0; mt < 4; mt++)
      #pragma unroll
      for (int nt = 0; nt < 2; nt++)
        acc[mt][nt] = __builtin_amdgcn_mfma_f32_16x16x32_bf16(a[mt], b[nt], acc[mt][nt], 0, 0, 0);
  }
  {
    float w256v[2], eb1v[2];
    #pragma unroll
    for (int nt = 0; nt < 2; nt++){
      int n = nb + nt*16 + ln;
      w256v[nt] = eW1[256 * H + n];
      eb1v[nt]  = eb1[n];
    }
    #pragma unroll
    for (int mt = 0; mt < 4; mt++)
      #pragma unroll
      for (int r = 0; r < 4; r++){
        int m = mt*16 + q*4 + r;
        float sq = sq_l[m];
        #pragma unroll
        for (int nt = 0; nt < 2; nt++){
          float x = acc[mt][nt][r] + sq * w256v[nt] + eb1v[nt];
          buf[m * 136 + nb + nt*16 + ln] = f2bf(silu_f(x));
        }
      }
  }
  __syncthreads();                                  // sync2: t1 ready in buf

  // ---- GEMM2: t1 @ eW2t -> m_ij
  #pragma unroll
  for (int mt = 0; mt < 4; mt++)
    #pragma unroll
    for (int nt = 0; nt < 2; nt++) acc[mt][nt] = (floatx4)0.f;
  #pragma unroll
  for (int ks = 0; ks < 4; ks++){
    short8 a[4], b[2];
    #pragma unroll
    for (int mt = 0; mt < 4; mt++)
      a[mt] = *(const short8*)(buf + (mt*16 + ln) * 136 + ks*32 + q*8);
    #pragma unroll
    for (int nt = 0; nt < 2; nt++)
      b[nt] = *(const short8*)(eW2t + (size_t)(nb + nt*16 + ln) * 128 + ks*32 + q*8);
    #pragma unroll
    for (int mt = 0; mt < 4; mt++)
      #pragma unroll
      for (int nt = 0; nt < 2; nt++)
        acc[mt][nt] = __builtin_amdgcn_mfma_f32_16x16x32_bf16(a[mt], b[nt], acc[mt][nt], 0, 0, 0);
  }
  __syncthreads();                                  // sync3: all t1 reads done
  {
    float eb2v[2];
    #pragma unroll
    for (int nt = 0; nt < 2; nt++) eb2v[nt] = eb2[nb + nt*16 + ln];
    #pragma unroll
    for (int mt = 0; mt < 4; mt++)
      #pragma unroll
      for (int r = 0; r < 4; r++){
        int m = mt*16 + q*4 + r;
        #pragma unroll
        for (int nt = 0; nt < 2; nt++){
          float mv = silu_f(acc[mt][nt][r] + eb2v[nt]);
          buf[m * 136 + nb + nt*16 + ln] = f2bf(mv);
        }
      }
  }
  __syncthreads();                                  // sync4: m_ij ready in buf

  // ---- GEMM3: m_ij @ cW1t ; dot with cW2 -> per-edge scalar weight
  #pragma unroll
  for (int mt = 0; mt < 4; mt++)
    #pragma unroll
    for (int nt = 0; nt < 2; nt++) acc[mt][nt] = (floatx4)0.f;
  #pragma unroll
  for (int ks = 0; ks < 4; ks++){
    short8 a[4], b[2];
    #pragma unroll
    for (int mt = 0; mt < 4; mt++)
      a[mt] = *(const short8*)(buf + (mt*16 + ln) * 136 + ks*32 + q*8);
    #pragma unroll
    for (int nt = 0; nt < 2; nt++)
      b[nt] = *(const short8*)(cW1t + (size_t)(nb + nt*16 + ln) * 128 + ks*32 + q*8);
    #pragma unroll
    for (int mt = 0; mt < 4; mt++)
      #pragma unroll
      for (int nt = 0; nt < 2; nt++)
        acc[mt][nt] = __builtin_amdgcn_mfma_f32_16x16x32_bf16(a[mt], b[nt], acc[mt][nt], 0, 0, 0);
  }
  {
    float cb1v[2], cw2v[2];
    #pragma unroll
    for (int nt = 0; nt < 2; nt++){
      int n = nb + nt*16 + ln;
      cb1v[nt] = cb1[n];
      cw2v[nt] = cW2[n];
    }
    #pragma unroll
    for (int mt = 0; mt < 4; mt++)
      #pragma unroll
      for (int r = 0; r < 4; r++){
        float p = 0.f;
        #pragma unroll
        for (int nt = 0; nt < 2; nt++)
          p += silu_f(acc[mt][nt][r] + cb1v[nt]) * cw2v[nt];
        p += __shfl_xor(p, 1);
        p += __shfl_xor(p, 2);
        p += __shfl_xor(p, 4);
        p += __shfl_xor(p, 8);
        if (ln == 0) atomicAdd(&w_l[mt*16 + q*4 + r], p);
      }
  }
  __syncthreads();                                  // sync5: w_l ready, buf=m_ij

  // ---- segmented reduce m_ij (rows sorted) -> m_i; 256 threads, 1 col each
  {
    int col = t & 127;
    int ms  = (t >> 7) * 32;
    float a0 = 0.f;
    int cur = row_l[ms];
    #pragma unroll 4
    for (int mm = 0; mm < 32; mm++){
      int m = ms + mm;
      int rr = row_l[m];
      float v = bf2f(buf[m * 136 + col]);
      if (rr != cur){
        unsafeAtomicAdd(&m_i[(size_t)cur * H + col], a0);
        a0 = 0.f; cur = rr;
      }
      a0 += v;
    }
    unsafeAtomicAdd(&m_i[(size_t)cur * H + col], a0);
  }
  // ---- pos segmented reduce with inline scaling (3 threads)
  if (t < 3){
    const float* src = (t == 0) ? dx_l : (t == 1) ? dy_l : dz_l;
    float accv = 0.f;
    int cur = row_l[0];
    for (int m = 0; m < TILE; m++){
      int rr = row_l[m];
      if (rr != cur){
        unsafeAtomicAdd(&pos_sum[cur*3 + t], accv);
        accv = 0.f; cur = rr;
      }
      float s = __builtin_amdgcn_rsqf(sq_l[m] + 1e-8f) * w_l[m];
      accv += src[m] * s;
    }
    unsafeAtomicAdd(&pos_sum[cur*3 + t], accv);
  }
}

// ---------------- node kernel ----------------------------------------------
__global__ __launch_bounds__(256, 3) void node_kernel(
    const float* __restrict__ h, const ushort_t* __restrict__ hb,
    const float* __restrict__ pos,
    const float* __restrict__ nb1, const float* __restrict__ nb2,
    const ushort_t* __restrict__ nW1t, const ushort_t* __restrict__ nW2t,
    const float* __restrict__ m_i, const float* __restrict__ pos_sum,
    const int* __restrict__ hist,
    float* __restrict__ h_out, float* __restrict__ pos_out)
{
  __shared__ __align__(16) ushort_t bufA[TILE * 264];
  __shared__ __align__(16) ushort_t bufT[TILE * 136];
  const int t = threadIdx.x;
  const int base = blockIdx.x * TILE;

  if (t < TILE){
    int node = base + t;
    if (node < NNODES){
      float c = fmaxf((float)hist[node], 1.f);
      float invc = __builtin_amdgcn_rcpf(c);
      pos_out[node*3+0] = pos[node*3+0] + pos_sum[node*3+0] * invc;
      pos_out[node*3+1] = pos[node*3+1] + pos_sum[node*3+1] * invc;
      pos_out[node*3+2] = pos[node*3+2] + pos_sum[node*3+2] * invc;
    }
  }
  { // gather [h(bf16 copy) | m_i(convert)] -> bufA
    const int i = t >> 2, p = t & 3;
    const int node = base + i;
    ushort_t* dst = bufA + i * 264 + p * 64;
    if (node < NNODES){
      if (p < 2){
        const short8* sp = (const short8*)(hb + (size_t)node * H + p * 64);
        #pragma unroll
        for (int j = 0; j < 8; j++) ((short8*)dst)[j] = sp[j];
      } else {
        const float4* sp = (const float4*)(m_i + (size_t)node * H + (p - 2) * 64);
        #pragma unroll
        for (int j = 0; j < 16; j++){
          float4 v = sp[j];
          dst[j*4+0] = f2bf(v.x); dst[j*4+1] = f2bf(v.y);
          dst[j*4+2] = f2bf(v.z); dst[j*4+3] = f2bf(v.w);
        }
      }
    } else {
      #pragma unroll
      for (int j = 0; j < 8; j++) ((short8*)dst)[j] = (short8)0;
    }
  }
  __syncthreads();

  const int lane = t & 63, q = lane >> 4, ln = lane & 15;
  const int nb_ = (t >> 6) * 32;

  floatx4 acc[4][2];
  #pragma unroll
  for (int mt = 0; mt < 4; mt++)
    #pragma unroll
    for (int nt = 0; nt < 2; nt++) acc[mt][nt] = (floatx4)0.f;
  #pragma unroll
  for (int ks = 0; ks < 8; ks++){
    short8 a[4], b[2];
    #pragma unroll
    for (int mt = 0; mt < 4; mt++)
      a[mt] = *(const short8*)(bufA + (mt*16 + ln) * 264 + ks*32 + q*8);
    #pragma unroll
    for (int nt = 0; nt < 2; nt++)
      b[nt] = *(const short8*)(nW1t + (size_t)(nb_ + nt*16 + ln) * 256 + ks*32 + q*8);
    #pragma unroll
    for (int mt = 0; mt < 4; mt++)
      #pragma unroll
      for (int nt = 0; nt < 2; nt++)
        acc[mt][nt] = __builtin_amdgcn_mfma_f32_16x16x32_bf16(a[mt], b[nt], acc[mt][nt], 0, 0, 0);
  }
  {
    float nb1v[2];
    #pragma unroll
    for (int nt = 0; nt < 2; nt++) nb1v[nt] = nb1[nb_ + nt*16 + ln];
    #pragma unroll
    for (int mt = 0; mt < 4; mt++)
      #pragma unroll
      for (int r = 0; r < 4; r++){
        int m = mt*16 + q*4 + r;
        #pragma unroll
        for (int nt = 0; nt < 2; nt++)
          bufT[m * 136 + nb_ + nt*16 + ln] = f2bf(silu_f(acc[mt][nt][r] + nb1v[nt]));
      }
  }
  __syncthreads();

  #pragma unroll
  for (int mt = 0; mt < 4; mt++)
    #pragma unroll
    for (int nt = 0; nt < 2; nt++) acc[mt][nt] = (floatx4)0.f;
  #pragma unroll
  for (int ks = 0; ks < 4; ks++){
    short8 a[4], b[2];
    #pragma unroll
    for (int mt = 0; mt < 4; mt++)
      a[mt] = *(const short8*)(bufT + (mt*16 + ln) * 136 + ks*32 + q*8);
    #pragma unroll
    for (int nt = 0; nt < 2; nt++)
      b[nt] = *(const short8*)(nW2t + (size_t)(nb_ + nt*16 + ln) * 128 + ks*32 + q*8);
    #pragma unroll
    for (int mt = 0; mt < 4; mt++)
      #pragma unroll
      for (int nt = 0; nt < 2; nt++)
        acc[mt][nt] = __builtin_amdgcn_mfma_f32_16x16x32_bf16(a[mt], b[nt], acc[mt][nt], 0, 0, 0);
  }
  {
    float nb2v[2];
    #pragma unroll
    for (int nt = 0; nt < 2; nt++) nb2v[nt] = nb2[nb_ + nt*16 + ln];
    #pragma unroll
    for (int mt = 0; mt < 4; mt++)
      #pragma unroll
      for (int r = 0; r < 4; r++){
        int m = mt*16 + q*4 + r;
        int node = base + m;
        if (node < NNODES){
          #pragma unroll
          for (int nt = 0; nt < 2; nt++){
            int n = nb_ + nt*16 + ln;
            h_out[(size_t)node * H + n] = h[(size_t)node * H + n] + acc[mt][nt][r] + nb2v[nt];
          }
        }
      }
  }
}

// ---------------- launch ----------------------------------------------------
extern "C" void kernel_launch(void* const* d_in, const int* in_sizes, int n_in,
                              void* d_out, int out_size, void* d_ws, size_t ws_size,
                              hipStream_t stream){
  const float* h   = (const float*)d_in[0];
  const float* pos = (const float*)d_in[1];
  const int*   ei  = (const int*)d_in[2];
  const float* eW1 = (const float*)d_in[3];
  const float* eb1 = (const float*)d_in[4];
  const float* eW2 = (const float*)d_in[5];
  const float* eb2 = (const float*)d_in[6];
  const float* cW1 = (const float*)d_in[7];
  const float* cb1 = (const float*)d_in[8];
  const float* cW2 = (const float*)d_in[9];
  const float* nW1 = (const float*)d_in[10];
  const float* nb1 = (const float*)d_in[11];
  const float* nW2 = (const float*)d_in[12];
  const float* nb2 = (const float*)d_in[13];

  char* ws = (char*)d_ws;
  float*    m_i     = (float*)   (ws);                 // 10,240,000 B
  float*    pos_sum = (float*)   (ws + 10240000);      //    240,000 B
  int*      hist    = (int*)     (ws + 10480000);      //     80,000 B
  int*      head    = (int*)     (ws + 10560000);      //     80,000 B
  int*      totals  = (int*)     (ws + 10640000);      //      2,048 B
  int2*     spair   = (int2*)    (ws + 10644096);      //  5,120,000 B
  ushort_t* h_bf    = (ushort_t*)(ws + 15764096);      //  5,120,000 B
  ushort_t* eW1t    = (ushort_t*)(ws + 20884096);      //     65,536 B
  ushort_t* eW2t    = (ushort_t*)(ws + 20949632);      //     32,768 B
  ushort_t* cW1t    = (ushort_t*)(ws + 20982400);      //     32,768 B
  ushort_t* nW1t    = (ushort_t*)(ws + 21015168);      //     65,536 B
  ushort_t* nW2t    = (ushort_t*)(ws + 21080704);      //     32,768 B

  hipMemsetAsync(hist, 0, 80000, stream);              // hist only; m_i/pos_sum zeroed in setup

  // threads: 1,074,688 (weights+h+hist) + 655,000 (zero m_i/pos_sum) = 1,729,688
  setup_kernel<<<6757, 256, 0, stream>>>(eW1, eW2, cW1, nW1, nW2, h, ei,
                                         eW1t, eW2t, cW1t, nW1t, nW2t, h_bf, hist,
                                         (float4*)ws);
  scanA_kernel<<<SCAN_BLOCKS, 1024, 0, stream>>>(hist, head, totals);
  scanC_kernel<<<SCAN_BLOCKS, 1024, 0, stream>>>(totals, head);
  scatter_kernel<<<(NEDGES + 255) / 256, 256, 0, stream>>>(ei, head, spair);

  edge_kernel<<<NEDGES / TILE, 256, 0, stream>>>(h_bf, pos, spair,
                                                 eW1, eb1, eb2, cb1, cW2,
                                                 eW1t, eW2t, cW1t, m_i, pos_sum);

  float* h_out   = (float*)d_out;
  float* pos_out = h_out + (size_t)NNODES * H;
  node_kernel<<<(NNODES + TILE - 1) / TILE, 256, 0, stream>>>(h, h_bf, pos, nb1, nb2,
                                                              nW1t, nW2t, m_i, pos_sum,
                                                              hist, h_out, pos_out);
}